// Round 7
// baseline (254.195 us; speedup 1.0000x reference)
//
#include <hip/hip_runtime.h>

#define B_DIM 4
#define T_DIM 300
#define U_DIM 80
#define UP1   81
#define V_DIM 1024
#define NINNER 512
#define NROWS (B_DIM * T_DIM * UP1)   /* 97200 */
#define EP_ROWS (B_DIM * T_DIM)       /* 1200 */
#define DP_ROWS (B_DIM * UP1)         /* 324 */
#define NDIAG_B 380                    /* t+u diagonals for lpb */
#define NDIAG_E 379                    /* t+u diagonals for lpe */
#define WF_PART 163840                 /* 512 cols x 320 k, per half of Wf */
#define LOG2E 1.44269504088896341f
#define LN2   0.69314718055994531f

typedef float f32x4 __attribute__((ext_vector_type(4)));
typedef short short8 __attribute__((ext_vector_type(8)));
typedef short short4v __attribute__((ext_vector_type(4)));
typedef __bf16 bf16x8 __attribute__((ext_vector_type(8)));

static __device__ __forceinline__ short f2bf(float f) {
  return (short)__builtin_bit_cast(unsigned short, (__bf16)f);  // native cvt (RNE)
}
static __device__ __forceinline__ float bf2f(short s) {
  unsigned int u = ((unsigned int)(unsigned short)s) << 16;
  return __builtin_bit_cast(float, u);
}
static __device__ __forceinline__ float fexp(float x) {
  return __builtin_amdgcn_exp2f(x * LOG2E);
}
static __device__ __forceinline__ float flog(float x) {
  return __builtin_amdgcn_logf(x) * LN2;
}
static __device__ __forceinline__ float tanh_fast(float x) {
  float e = __builtin_amdgcn_exp2f(x * 2.88539008177792681f); // exp(2x)
  return 1.0f - 2.0f * __builtin_amdgcn_rcpf(e + 1.0f);
}

// ---------------- Kernel 0: weights fp32 -> bf16, MFMA-frag-linear pack -----
// B-matrix element (c,k) -> frag=(c>>4)*KB+(k>>5); lane=((k>>3)&3)*16+(c&15);
// offset = frag*512 + lane*8 + (k&7). A B-fragment load is then lane-linear:
// one coalesced 1 KB global_load_dwordx4 (fixes r4's 16-line scatter).
__global__ __launch_bounds__(256) void cvt_kernel(
    const float* __restrict__ Wf, const float* __restrict__ Wp,
    short* __restrict__ WfB, short* __restrict__ WpB) {
  int idx = blockIdx.x * 256 + threadIdx.x;
  const int nf = (512 * 640) / 4;   // 81920
  const int np = (V_DIM * NINNER) / 4;
  if (idx < nf) {
    float4 v = ((const float4*)Wf)[idx];
    int flat = idx * 4;
    int c = flat / 640;
    int kc = flat - c * 640;
    int part = (kc >= 320);
    int k0 = kc - (part ? 320 : 0);
    int dest = (part ? WF_PART : 0)
             + ((c >> 4) * 10 + (k0 >> 5)) * 512
             + (((k0 >> 3) & 3) * 16 + (c & 15)) * 8 + (k0 & 7);
    short4v o;
    o[0] = f2bf(v.x); o[1] = f2bf(v.y); o[2] = f2bf(v.z); o[3] = f2bf(v.w);
    *(short4v*)(WfB + dest) = o;
  } else if (idx < nf + np) {
    int j = idx - nf;
    float4 v = ((const float4*)Wp)[j];
    int flat = j * 4;
    int c = flat >> 9;
    int k0 = flat & 511;
    int dest = ((c >> 4) * 16 + (k0 >> 5)) * 512
             + (((k0 >> 3) & 3) * 16 + (c & 15)) * 8 + (k0 & 7);
    short4v o;
    o[0] = f2bf(v.x); o[1] = f2bf(v.y); o[2] = f2bf(v.z); o[3] = f2bf(v.w);
    *(short4v*)(WpB + dest) = o;
  }
}

// ---------------- Kernel 1: enc/dec projections (MFMA bf16) ----------------
// grid = 50: bid = ob*2+half. ob<19: ep rows; else dp rows (bf added).
// Output ep/dp in bf16 (halves joint's Phase-A load bytes, r7).
// NOTE: no min-waves arg — min-waves>=4 on MFMA kernels splits the unified
// RF (Arch 64 / AGPR 64) and spills (r2/r3).
#define EP_BLOCKS 19
__global__ __launch_bounds__(256) void proj_kernel(
    const float* __restrict__ enc, const float* __restrict__ dec,
    const short* __restrict__ WfB, const float* __restrict__ bfv,
    short* __restrict__ epB, short* __restrict__ dpB) {
  const int half = blockIdx.x & 1;
  const int ob = blockIdx.x >> 1;
  const bool is_dp = (ob >= EP_BLOCKS);
  const int row0 = (is_dp ? ob - EP_BLOCKS : ob) * 64;
  const int nrows = is_dp ? DP_ROWS : EP_ROWS;
  const float* __restrict__ src = is_dp ? dec : enc;
  const short* __restrict__ bb = WfB + (is_dp ? WF_PART : 0);  // packed
  short* __restrict__ out = is_dp ? dpB : epB;

  __shared__ short As[64 * 320];  // 40 KB, XOR-swizzled
  const int tid = threadIdx.x;

  #pragma unroll
  for (int it = 0; it < 10; ++it) {
    int chunk = it * 256 + tid;        // 2560 chunks of 8 elems
    int m = chunk / 40;
    int c = chunk - m * 40;
    int r = row0 + m;
    short8 hv;
    #pragma unroll
    for (int j = 0; j < 8; ++j) hv[j] = 0;
    if (r < nrows) {
      const float* p = src + (size_t)r * 320 + c * 8;
      float4 a0 = *(const float4*)p;
      float4 a1 = *(const float4*)(p + 4);
      hv[0] = f2bf(a0.x); hv[1] = f2bf(a0.y); hv[2] = f2bf(a0.z); hv[3] = f2bf(a0.w);
      hv[4] = f2bf(a1.x); hv[5] = f2bf(a1.y); hv[6] = f2bf(a1.z); hv[7] = f2bf(a1.w);
    }
    int off = (m * 640 + c * 16) ^ ((m & 7) << 4);
    *(short8*)((char*)As + off) = hv;
  }
  __syncthreads();

  const int lane = tid & 63, wid = tid >> 6;
  const int lr = lane & 15, g = lane >> 4;

  int lin[4], xm[4];
  #pragma unroll
  for (int mf = 0; mf < 4; ++mf) {
    int row = mf * 16 + lr;
    lin[mf] = row * 640 + g * 16;
    xm[mf] = (row & 7) << 4;
  }

  const int n0 = half * 256 + wid * 64;
  const short* bptr[4];
  float bfc[4];
  #pragma unroll
  for (int nf2 = 0; nf2 < 4; ++nf2) {
    bptr[nf2] = bb + (n0 / 16 + nf2) * 5120 + lane * 8;   // frag-linear
    bfc[nf2] = is_dp ? bfv[n0 + nf2 * 16 + lr] : 0.f;
  }
  f32x4 acc[4][4];
  #pragma unroll
  for (int mf = 0; mf < 4; ++mf)
    #pragma unroll
    for (int nf2 = 0; nf2 < 4; ++nf2)
      acc[mf][nf2] = (f32x4){0.f, 0.f, 0.f, 0.f};

  #pragma unroll 2
  for (int kk = 0; kk < 10; ++kk) {
    bf16x8 av[4], bv[4];
    #pragma unroll
    for (int mf = 0; mf < 4; ++mf) {
      int off = (lin[mf] + (kk << 6)) ^ xm[mf];
      av[mf] = __builtin_bit_cast(bf16x8, *(const short8*)((const char*)As + off));
    }
    #pragma unroll
    for (int nf2 = 0; nf2 < 4; ++nf2)
      bv[nf2] = __builtin_bit_cast(bf16x8, *(const short8*)(bptr[nf2] + kk * 512));
    #pragma unroll
    for (int mf = 0; mf < 4; ++mf)
      #pragma unroll
      for (int nf2 = 0; nf2 < 4; ++nf2)
        acc[mf][nf2] = __builtin_amdgcn_mfma_f32_16x16x32_bf16(av[mf], bv[nf2], acc[mf][nf2], 0, 0, 0);
  }
  #pragma unroll
  for (int mf = 0; mf < 4; ++mf)
    #pragma unroll
    for (int nf2 = 0; nf2 < 4; ++nf2)
      #pragma unroll
      for (int rr = 0; rr < 4; ++rr) {
        int rowl = mf * 16 + g * 4 + rr;
        int grow = row0 + rowl;
        if (grow < nrows) {
          int col = n0 + nf2 * 16 + lr;
          out[(size_t)grow * NINNER + col] = f2bf(acc[mf][nf2][rr] + bfc[nf2]);
        }
      }
}

// ---------------- Kernel 2: fused joint + log-softmax slices ----------------
// 512 threads (8 waves), 64 rows x V=1024; wave w owns cols [w*128,(w+1)*128)
// as 2 subchunks of 64; mf=4 -> each B-frag feeds 4 MFMA. B reads are
// frag-linear coalesced. Base-2 softmax: x = fma(acc, log2e, bp*log2e);
// sum exp2(x); lse2 = log2(S); outputs (x - lse2)*ln2.  (r7: VALU diet)
#define JROWS 64
__global__ __launch_bounds__(512) void joint_kernel(
    const short* __restrict__ epB, const short* __restrict__ dpB,
    const short* __restrict__ WpB, const float* __restrict__ bp,
    const int* __restrict__ tgt,
    float* __restrict__ lpb_d, float* __restrict__ lpe_d) {
  extern __shared__ char hbuf[];  // 64 * 512 * 2 = 65536 B
  __shared__ int ep_off[JROWS], dp_off[JROWS], bld_off[JROWS], eld_off[JROWS], tgt_s[JROWS];
  __shared__ float l0_s[JROWS], lt_s[JROWS];
  __shared__ float ws_s[8][JROWS];

  const int tid = threadIdx.x;
  const int row0 = blockIdx.x * JROWS;

  if (tid < JROWS) {
    int gr = row0 + tid;
    if (gr < NROWS) {
      int b = gr / (T_DIM * UP1);
      int rem = gr - b * (T_DIM * UP1);
      int t = rem / UP1;
      int u = rem - t * UP1;
      ep_off[tid] = (b * T_DIM + t) * NINNER;
      dp_off[tid] = (b * UP1 + u) * NINNER;
      bld_off[tid] = (b * NDIAG_B + (t + u)) * UP1 + u;          // diag layout
      eld_off[tid] = (u < U_DIM) ? ((b * NDIAG_E + (t + u)) * U_DIM + u) : -1;
      tgt_s[tid] = (u < U_DIM) ? tgt[b * U_DIM + u] : 0;
    } else {
      ep_off[tid] = 0; dp_off[tid] = 0; bld_off[tid] = -1; eld_off[tid] = -1; tgt_s[tid] = 0;
    }
    l0_s[tid] = 0.f; lt_s[tid] = 0.f;
  }
  __syncthreads();

  // Phase A: h = tanh(ep+dp) into LDS (bf16 in, bf16 out, swizzled)
  #pragma unroll 2
  for (int it = 0; it < 8; ++it) {
    int chunk = it * 512 + tid;    // 4096 chunks of 8
    int m = chunk >> 6, c = chunk & 63;
    short8 hv;
    #pragma unroll
    for (int j = 0; j < 8; ++j) hv[j] = 0;
    if (bld_off[m] >= 0) {
      short8 ev = *(const short8*)(epB + ep_off[m] + c * 8);
      short8 dv = *(const short8*)(dpB + dp_off[m] + c * 8);
      #pragma unroll
      for (int j = 0; j < 8; ++j)
        hv[j] = f2bf(tanh_fast(bf2f(ev[j]) + bf2f(dv[j])));
    }
    int off = ((m << 10) + (c << 4)) ^ ((m & 7) << 4);
    *(short8*)(hbuf + off) = hv;
  }
  __syncthreads();

  const int lane = tid & 63, wid = tid >> 6;
  const int lr = lane & 15, g = lane >> 4;

  int lin[4], xm[4];
  #pragma unroll
  for (int mf = 0; mf < 4; ++mf) {
    int row = mf * 16 + lr;
    lin[mf] = (row << 10) + (g << 4);
    xm[mf] = (row & 7) << 4;
  }
  int tv[4][4];
  #pragma unroll
  for (int mf = 0; mf < 4; ++mf)
    #pragma unroll
    for (int rr = 0; rr < 4; ++rr)
      tv[mf][rr] = tgt_s[mf * 16 + g * 4 + rr];

  float rsum[4][4];
  #pragma unroll
  for (int mf = 0; mf < 4; ++mf)
    #pragma unroll
    for (int rr = 0; rr < 4; ++rr) rsum[mf][rr] = 0.f;

  #pragma unroll
  for (int sc = 0; sc < 2; ++sc) {
    const int n0 = wid * 128 + sc * 64;
    const short* bptr[4];
    float bpv[4];
    #pragma unroll
    for (int nf = 0; nf < 4; ++nf) {
      bptr[nf] = WpB + (n0 / 16 + nf) * 8192 + lane * 8;   // frag-linear
      bpv[nf] = bp[n0 + nf * 16 + lr] * LOG2E;             // scaled bias
    }
    f32x4 acc[4][4];
    #pragma unroll
    for (int mf = 0; mf < 4; ++mf)
      #pragma unroll
      for (int nf = 0; nf < 4; ++nf)
        acc[mf][nf] = (f32x4){0.f, 0.f, 0.f, 0.f};

    #pragma unroll 2
    for (int kk = 0; kk < 16; ++kk) {
      bf16x8 av[4], bv[4];
      #pragma unroll
      for (int mf = 0; mf < 4; ++mf) {
        int off = (lin[mf] + (kk << 6)) ^ xm[mf];
        av[mf] = __builtin_bit_cast(bf16x8, *(const short8*)(hbuf + off));
      }
      #pragma unroll
      for (int nf = 0; nf < 4; ++nf)
        bv[nf] = __builtin_bit_cast(bf16x8, *(const short8*)(bptr[nf] + kk * 512));
      #pragma unroll
      for (int mf = 0; mf < 4; ++mf)
        #pragma unroll
        for (int nf = 0; nf < 4; ++nf)
          acc[mf][nf] = __builtin_amdgcn_mfma_f32_16x16x32_bf16(av[mf], bv[nf], acc[mf][nf], 0, 0, 0);
    }
    // fold: base-2 sum-of-exp2 over this 64-col subchunk (scaled logits)
    #pragma unroll
    for (int mf = 0; mf < 4; ++mf)
      #pragma unroll
      for (int rr = 0; rr < 4; ++rr) {
        float x0 = __builtin_fmaf(acc[mf][0][rr], LOG2E, bpv[0]);
        float x1 = __builtin_fmaf(acc[mf][1][rr], LOG2E, bpv[1]);
        float x2 = __builtin_fmaf(acc[mf][2][rr], LOG2E, bpv[2]);
        float x3 = __builtin_fmaf(acc[mf][3][rr], LOG2E, bpv[3]);
        int rowl = mf * 16 + g * 4 + rr;
        if (wid == 0 && sc == 0 && lr == 0) l0_s[rowl] = x0;  // v = 0 (scaled)
        int dtv = tv[mf][rr] - n0;
        if (dtv >= 0 && dtv < 64 && (dtv & 15) == lr) {
          int nfi = dtv >> 4;
          lt_s[rowl] = (nfi == 0) ? x0 : (nfi == 1) ? x1 : (nfi == 2) ? x2 : x3;
        }
        rsum[mf][rr] += __builtin_amdgcn_exp2f(x0) + __builtin_amdgcn_exp2f(x1)
                      + __builtin_amdgcn_exp2f(x2) + __builtin_amdgcn_exp2f(x3);
      }
  }
  // add-butterfly across the 16 lanes of each group
  #pragma unroll
  for (int mf = 0; mf < 4; ++mf)
    #pragma unroll
    for (int rr = 0; rr < 4; ++rr) {
      float s_ = rsum[mf][rr];
      #pragma unroll
      for (int o = 1; o < 16; o <<= 1) s_ += __shfl_xor(s_, o);
      if (lr == 0) ws_s[wid][mf * 16 + g * 4 + rr] = s_;
    }
  __syncthreads();
  if (tid < JROWS) {
    int bo = bld_off[tid];
    if (bo >= 0) {
      float S = 0.f;
      #pragma unroll
      for (int w = 0; w < 8; ++w) S += ws_s[w][tid];
      float lse2 = __builtin_amdgcn_logf(S);  // log2
      lpb_d[bo] = (l0_s[tid] - lse2) * LN2;
      int eo = eld_off[tid];
      if (eo >= 0) lpe_d[eo] = (lt_s[tid] - lse2) * LN2;
    }
  }
}

// ---------------- Kernel 3: alpha wavefront DP + loss ----------------
// 1 block x 256 threads; wave w owns batch b=w, fully independent (no
// __syncthreads anywhere). Chunked 16 diagonals, LDS double-buffered:
// issue next chunk's global loads (no wait) -> 16 serial steps from LDS ->
// vmcnt-wait + ds_write next chunk (covered by the 16 steps). (r6, validated)
#define ACHUNK 16
#define NCHUNK 24   /* 24*16 = 384 >= 380 steps; extra steps compute NEG */
#define LB_FLOATS (ACHUNK * UP1)    /* 1296 */
#define LE_FLOATS (ACHUNK * U_DIM)  /* 1280 */
#define LE_BASE   (2 * B_DIM * LB_FLOATS) /* 10368 */
__global__ __launch_bounds__(256) void alpha_kernel(
    const float* __restrict__ lpb_d, const float* __restrict__ lpe_d,
    const int* __restrict__ ilen, const int* __restrict__ ulen_,
    float* __restrict__ out) {
  extern __shared__ float sbuf[];  // 82432 B: Lb[2][4][1296] + Le[2][4][1280]
  __shared__ float lls[B_DIM];
  const int tid = threadIdx.x;
  const int b = tid >> 6;
  const int lane = tid & 63;
  const float NEG = -1e30f;
  const int tl = ilen[b], ul = ulen_[b];

  const int u0 = lane;           // slot 0: u = 0..63
  const int u1 = 64 + lane;      // slot 1: u = 64..80 (lane < 17)
  const bool act1 = (u1 <= 80);

  const float* pb = lpb_d + (size_t)b * (NDIAG_B * UP1);
  const float4* pb4 = (const float4*)pb;
  const float4* pe4 = (const float4*)(lpe_d + (size_t)b * (NDIAG_E * U_DIM));
  const int PB4MAX = (NDIAG_B * UP1) / 4 - 1;   // 7694
  const int PE4MAX = (NDIAG_E * U_DIM) / 4 - 1; // 7579

  float4 rb[6], re[5];

  #define LOAD_CHUNK(c)                                                     \
    {                                                                       \
      int gb_ = (c) * (LB_FLOATS / 4), ge_ = (c) * (LE_FLOATS / 4);         \
      _Pragma("unroll")                                                     \
      for (int i = 0; i < 6; ++i) {                                         \
        int v = i * 64 + lane;                                              \
        if (v < LB_FLOATS / 4) {                                            \
          int gv = gb_ + v; if (gv > PB4MAX) gv = PB4MAX;                   \
          rb[i] = pb4[gv];                                                  \
        }                                                                   \
      }                                                                     \
      _Pragma("unroll")                                                     \
      for (int i = 0; i < 5; ++i) {                                         \
        int v = i * 64 + lane;                                              \
        int gv = ge_ + v; if (gv > PE4MAX) gv = PE4MAX;                     \
        re[i] = pe4[gv];                                                    \
      }                                                                     \
    }
  #define WRITE_CHUNK(c)                                                    \
    {                                                                       \
      int h_ = (c) & 1;                                                     \
      float* Lb_ = sbuf + (h_ * B_DIM + b) * LB_FLOATS;                     \
      float* Le_ = sbuf + LE_BASE + (h_ * B_DIM + b) * LE_FLOATS;           \
      _Pragma("unroll")                                                     \
      for (int i = 0; i < 6; ++i) {                                         \
        int v = i * 64 + lane;                                              \
        if (v < LB_FLOATS / 4) *(float4*)(Lb_ + v * 4) = rb[i];             \
      }                                                                     \
      _Pragma("unroll")                                                     \
      for (int i = 0; i < 5; ++i) {                                         \
        int v = i * 64 + lane;                                              \
        *(float4*)(Le_ + v * 4) = re[i];                                    \
      }                                                                     \
    }

  LOAD_CHUNK(0);
  WRITE_CHUNK(0);

  float pa0 = (u0 == 0) ? 0.f : NEG;  // alpha on diag 0
  float pa1 = NEG;
  float fin = NEG;

  for (int c = 0; c < NCHUNK; ++c) {
    if (c + 1 < NCHUNK) LOAD_CHUNK(c + 1);   // issue early, no wait
    const int h = c & 1;
    const float* Lb = sbuf + (h * B_DIM + b) * LB_FLOATS;
    const float* Le = sbuf + LE_BASE + (h * B_DIM + b) * LE_FLOATS;
    #pragma unroll
    for (int j = 0; j < ACHUNK; ++j) {
      const int d = c * ACHUNK + j + 1;
      float bl0 = Lb[j * UP1 + u0];
      float em0 = (u0 >= 1) ? Le[j * U_DIM + u0 - 1] : NEG;
      float bl1 = act1 ? Lb[j * UP1 + u1] : NEG;
      float em1 = act1 ? Le[j * U_DIM + u1 - 1] : NEG;
      float n0t = __shfl(pa0, (lane + 63) & 63);
      float n1t = __shfl(pa1, (lane + 63) & 63);
      float n0_63 = __shfl(pa0, 63);
      // slot 0
      float v0;
      {
        int t = d - u0;
        bool cell = (t >= 0 && t <= T_DIM - 1);
        float a = (cell && t >= 1) ? pa0 + bl0 : NEG;
        float e = (cell && u0 >= 1) ? n0t + em0 : NEG;
        float mx = fmaxf(a, e), mn = fminf(a, e);
        v0 = cell ? mx + flog(1.0f + fexp(mn - mx)) : NEG;
        if (u0 == ul && t == tl - 1) fin = v0;
      }
      // slot 1
      {
        int t = d - u1;
        float nem = (lane == 0) ? n0_63 : n1t;
        bool cell = act1 && (t >= 0 && t <= T_DIM - 1);
        float a = (cell && t >= 1) ? pa1 + bl1 : NEG;
        float e = cell ? nem + em1 : NEG;   // u1 >= 64 >= 1 always
        float mx = fmaxf(a, e), mn = fminf(a, e);
        float v1 = cell ? mx + flog(1.0f + fexp(mn - mx)) : NEG;
        if (act1 && u1 == ul && t == tl - 1) fin = v1;
        pa1 = v1;
      }
      pa0 = v0;
    }
    if (c + 1 < NCHUNK) WRITE_CHUNK(c + 1);  // vmcnt wait lands here, covered
  }

  #pragma unroll
  for (int o = 32; o; o >>= 1) fin = fmaxf(fin, __shfl_xor(fin, o));
  if (lane == 0) {
    float last = pb[(size_t)(tl - 1 + ul) * UP1 + ul];
    lls[b] = fin + last;
  }
  __syncthreads();
  if (tid == 0)
    out[0] = -(lls[0] + lls[1] + lls[2] + lls[3]) * (1.0f / (float)B_DIM);
}

// ---------------- launcher ----------------
extern "C" void kernel_launch(void* const* d_in, const int* in_sizes, int n_in,
                              void* d_out, int out_size, void* d_ws, size_t ws_size,
                              hipStream_t stream) {
  const float* enc = (const float*)d_in[0];
  const float* dec = (const float*)d_in[1];
  const float* Wf  = (const float*)d_in[2];
  const float* bfv = (const float*)d_in[3];
  const float* Wp  = (const float*)d_in[4];
  const float* bp  = (const float*)d_in[5];
  const int* targets = (const int*)d_in[6];
  const int* ilen    = (const int*)d_in[7];
  const int* ulen    = (const int*)d_in[8];
  float* out = (float*)d_out;
  char* ws = (char*)d_ws;

  short* WfB   = (short*)(ws + 0);          //   655360 B (packed)
  short* WpB   = (short*)(ws + 655360);     //  1048576 B (packed) -> 1703936
  short* epB   = (short*)(ws + 1703936);    //  1228800 B (bf16)   -> 2932736
  short* dpB   = (short*)(ws + 2932736);    //   331776 B (bf16)   -> 3264512
  float* lpb_d = (float*)(ws + 3264512);    //   492480 B (4*380*81) -> 3756992
  float* lpe_d = (float*)(ws + 3756992);    //   485120 B (4*379*80) -> 4242112

  cvt_kernel<<<832, 256, 0, stream>>>(Wf, Wp, WfB, WpB);
  proj_kernel<<<50, 256, 0, stream>>>(enc, dec, WfB, bfv, epB, dpB);
  joint_kernel<<<(NROWS + JROWS - 1) / JROWS, 512, 65536, stream>>>(epB, dpB, WpB, bp, targets, lpb_d, lpe_d);
  alpha_kernel<<<1, 256, 82432, stream>>>(lpb_d, lpe_d, ilen, ulen, out);
}

// Round 8
// 252.160 us; speedup vs baseline: 1.0081x; 1.0081x over previous
//
#include <hip/hip_runtime.h>

#define B_DIM 4
#define T_DIM 300
#define U_DIM 80
#define UP1   81
#define V_DIM 1024
#define NINNER 512
#define NROWS (B_DIM * T_DIM * UP1)   /* 97200 */
#define EP_ROWS (B_DIM * T_DIM)       /* 1200 */
#define DP_ROWS (B_DIM * UP1)         /* 324 */
#define NDIAG_B 380                    /* t+u diagonals for lpb */
#define NDIAG_E 379                    /* t+u diagonals for lpe */
#define WF_PART 163840                 /* 512 cols x 320 k, per half of Wf */
#define LOG2E 1.44269504088896341f
#define LN2   0.69314718055994531f

typedef float f32x4 __attribute__((ext_vector_type(4)));
typedef short short8 __attribute__((ext_vector_type(8)));
typedef short short4v __attribute__((ext_vector_type(4)));
typedef __bf16 bf16x8 __attribute__((ext_vector_type(8)));

static __device__ __forceinline__ short f2bf(float f) {
  return (short)__builtin_bit_cast(unsigned short, (__bf16)f);  // native cvt (RNE)
}
static __device__ __forceinline__ float bf2f(short s) {
  unsigned int u = ((unsigned int)(unsigned short)s) << 16;
  return __builtin_bit_cast(float, u);
}
static __device__ __forceinline__ float tanh_fast(float x) {
  float e = __builtin_amdgcn_exp2f(x * 2.88539008177792681f); // exp(2x)
  return 1.0f - 2.0f * __builtin_amdgcn_rcpf(e + 1.0f);
}
// base-2 logsumexp of 2 terms (NEG-safe)
static __device__ __forceinline__ float lse2_2(float a, float b) {
  float mx = fmaxf(a, b), mn = fminf(a, b);
  return mx + __builtin_amdgcn_logf(1.0f + __builtin_amdgcn_exp2f(mn - mx));
}

// ---------------- Kernel 0: weights fp32 -> bf16, MFMA-frag-linear pack -----
// B-matrix element (c,k) -> frag=(c>>4)*KB+(k>>5); lane=((k>>3)&3)*16+(c&15);
// offset = frag*512 + lane*8 + (k&7). A B-fragment load is then lane-linear:
// one coalesced 1 KB global_load_dwordx4 (fixes r4's 16-line scatter).
__global__ __launch_bounds__(256) void cvt_kernel(
    const float* __restrict__ Wf, const float* __restrict__ Wp,
    short* __restrict__ WfB, short* __restrict__ WpB) {
  int idx = blockIdx.x * 256 + threadIdx.x;
  const int nf = (512 * 640) / 4;   // 81920
  const int np = (V_DIM * NINNER) / 4;
  if (idx < nf) {
    float4 v = ((const float4*)Wf)[idx];
    int flat = idx * 4;
    int c = flat / 640;
    int kc = flat - c * 640;
    int part = (kc >= 320);
    int k0 = kc - (part ? 320 : 0);
    int dest = (part ? WF_PART : 0)
             + ((c >> 4) * 10 + (k0 >> 5)) * 512
             + (((k0 >> 3) & 3) * 16 + (c & 15)) * 8 + (k0 & 7);
    short4v o;
    o[0] = f2bf(v.x); o[1] = f2bf(v.y); o[2] = f2bf(v.z); o[3] = f2bf(v.w);
    *(short4v*)(WfB + dest) = o;
  } else if (idx < nf + np) {
    int j = idx - nf;
    float4 v = ((const float4*)Wp)[j];
    int flat = j * 4;
    int c = flat >> 9;
    int k0 = flat & 511;
    int dest = ((c >> 4) * 16 + (k0 >> 5)) * 512
             + (((k0 >> 3) & 3) * 16 + (c & 15)) * 8 + (k0 & 7);
    short4v o;
    o[0] = f2bf(v.x); o[1] = f2bf(v.y); o[2] = f2bf(v.z); o[3] = f2bf(v.w);
    *(short4v*)(WpB + dest) = o;
  }
}

// ---------------- Kernel 1: enc/dec projections (MFMA bf16) ----------------
// grid = 50: bid = ob*2+half. ob<19: ep rows; else dp rows (bf added).
// Output ep/dp in bf16. NOTE: no min-waves arg — min-waves>=4 on MFMA kernels
// splits the unified RF (Arch 64 / AGPR 64) and spills (r2/r3).
#define EP_BLOCKS 19
__global__ __launch_bounds__(256) void proj_kernel(
    const float* __restrict__ enc, const float* __restrict__ dec,
    const short* __restrict__ WfB, const float* __restrict__ bfv,
    short* __restrict__ epB, short* __restrict__ dpB) {
  const int half = blockIdx.x & 1;
  const int ob = blockIdx.x >> 1;
  const bool is_dp = (ob >= EP_BLOCKS);
  const int row0 = (is_dp ? ob - EP_BLOCKS : ob) * 64;
  const int nrows = is_dp ? DP_ROWS : EP_ROWS;
  const float* __restrict__ src = is_dp ? dec : enc;
  const short* __restrict__ bb = WfB + (is_dp ? WF_PART : 0);  // packed
  short* __restrict__ out = is_dp ? dpB : epB;

  __shared__ short As[64 * 320];  // 40 KB, XOR-swizzled
  const int tid = threadIdx.x;

  #pragma unroll
  for (int it = 0; it < 10; ++it) {
    int chunk = it * 256 + tid;        // 2560 chunks of 8 elems
    int m = chunk / 40;
    int c = chunk - m * 40;
    int r = row0 + m;
    short8 hv;
    #pragma unroll
    for (int j = 0; j < 8; ++j) hv[j] = 0;
    if (r < nrows) {
      const float* p = src + (size_t)r * 320 + c * 8;
      float4 a0 = *(const float4*)p;
      float4 a1 = *(const float4*)(p + 4);
      hv[0] = f2bf(a0.x); hv[1] = f2bf(a0.y); hv[2] = f2bf(a0.z); hv[3] = f2bf(a0.w);
      hv[4] = f2bf(a1.x); hv[5] = f2bf(a1.y); hv[6] = f2bf(a1.z); hv[7] = f2bf(a1.w);
    }
    int off = (m * 640 + c * 16) ^ ((m & 7) << 4);
    *(short8*)((char*)As + off) = hv;
  }
  __syncthreads();

  const int lane = tid & 63, wid = tid >> 6;
  const int lr = lane & 15, g = lane >> 4;

  int lin[4], xm[4];
  #pragma unroll
  for (int mf = 0; mf < 4; ++mf) {
    int row = mf * 16 + lr;
    lin[mf] = row * 640 + g * 16;
    xm[mf] = (row & 7) << 4;
  }

  const int n0 = half * 256 + wid * 64;
  const short* bptr[4];
  float bfc[4];
  #pragma unroll
  for (int nf2 = 0; nf2 < 4; ++nf2) {
    bptr[nf2] = bb + (n0 / 16 + nf2) * 5120 + lane * 8;   // frag-linear
    bfc[nf2] = is_dp ? bfv[n0 + nf2 * 16 + lr] : 0.f;
  }
  f32x4 acc[4][4];
  #pragma unroll
  for (int mf = 0; mf < 4; ++mf)
    #pragma unroll
    for (int nf2 = 0; nf2 < 4; ++nf2)
      acc[mf][nf2] = (f32x4){0.f, 0.f, 0.f, 0.f};

  #pragma unroll 2
  for (int kk = 0; kk < 10; ++kk) {
    bf16x8 av[4], bv[4];
    #pragma unroll
    for (int mf = 0; mf < 4; ++mf) {
      int off = (lin[mf] + (kk << 6)) ^ xm[mf];
      av[mf] = __builtin_bit_cast(bf16x8, *(const short8*)((const char*)As + off));
    }
    #pragma unroll
    for (int nf2 = 0; nf2 < 4; ++nf2)
      bv[nf2] = __builtin_bit_cast(bf16x8, *(const short8*)(bptr[nf2] + kk * 512));
    #pragma unroll
    for (int mf = 0; mf < 4; ++mf)
      #pragma unroll
      for (int nf2 = 0; nf2 < 4; ++nf2)
        acc[mf][nf2] = __builtin_amdgcn_mfma_f32_16x16x32_bf16(av[mf], bv[nf2], acc[mf][nf2], 0, 0, 0);
  }
  #pragma unroll
  for (int mf = 0; mf < 4; ++mf)
    #pragma unroll
    for (int nf2 = 0; nf2 < 4; ++nf2)
      #pragma unroll
      for (int rr = 0; rr < 4; ++rr) {
        int rowl = mf * 16 + g * 4 + rr;
        int grow = row0 + rowl;
        if (grow < nrows) {
          int col = n0 + nf2 * 16 + lr;
          out[(size_t)grow * NINNER + col] = f2bf(acc[mf][nf2][rr] + bfc[nf2]);
        }
      }
}

// ---------------- Kernel 2: fused joint + log-softmax slices ----------------
// 512 threads (8 waves), 64 rows x V=1024; wave w owns cols [w*128,(w+1)*128)
// as 2 subchunks of 64; mf=4 -> each B-frag feeds 4 MFMA. B reads are
// frag-linear coalesced. Base-2 softmax; OUTPUT IN LOG2 DOMAIN (lp/ln2) —
// alpha consumes base-2, final loss x ln2 (r8). T5 setprio around MFMA burst.
#define JROWS 64
__global__ __launch_bounds__(512) void joint_kernel(
    const short* __restrict__ epB, const short* __restrict__ dpB,
    const short* __restrict__ WpB, const float* __restrict__ bp,
    const int* __restrict__ tgt,
    float* __restrict__ lpb_d, float* __restrict__ lpe_d) {
  extern __shared__ char hbuf[];  // 64 * 512 * 2 = 65536 B
  __shared__ int ep_off[JROWS], dp_off[JROWS], bld_off[JROWS], eld_off[JROWS], tgt_s[JROWS];
  __shared__ float l0_s[JROWS], lt_s[JROWS];
  __shared__ float ws_s[8][JROWS];

  const int tid = threadIdx.x;
  const int row0 = blockIdx.x * JROWS;

  if (tid < JROWS) {
    int gr = row0 + tid;
    if (gr < NROWS) {
      int b = gr / (T_DIM * UP1);
      int rem = gr - b * (T_DIM * UP1);
      int t = rem / UP1;
      int u = rem - t * UP1;
      ep_off[tid] = (b * T_DIM + t) * NINNER;
      dp_off[tid] = (b * UP1 + u) * NINNER;
      bld_off[tid] = (b * NDIAG_B + (t + u)) * UP1 + u;          // diag layout
      eld_off[tid] = (u < U_DIM) ? ((b * NDIAG_E + (t + u)) * U_DIM + u) : -1;
      tgt_s[tid] = (u < U_DIM) ? tgt[b * U_DIM + u] : 0;
    } else {
      ep_off[tid] = 0; dp_off[tid] = 0; bld_off[tid] = -1; eld_off[tid] = -1; tgt_s[tid] = 0;
    }
    l0_s[tid] = 0.f; lt_s[tid] = 0.f;
  }
  __syncthreads();

  // Phase A: h = tanh(ep+dp) into LDS (bf16 in, bf16 out, swizzled)
  #pragma unroll 2
  for (int it = 0; it < 8; ++it) {
    int chunk = it * 512 + tid;    // 4096 chunks of 8
    int m = chunk >> 6, c = chunk & 63;
    short8 hv;
    #pragma unroll
    for (int j = 0; j < 8; ++j) hv[j] = 0;
    if (bld_off[m] >= 0) {
      short8 ev = *(const short8*)(epB + ep_off[m] + c * 8);
      short8 dv = *(const short8*)(dpB + dp_off[m] + c * 8);
      #pragma unroll
      for (int j = 0; j < 8; ++j)
        hv[j] = f2bf(tanh_fast(bf2f(ev[j]) + bf2f(dv[j])));
    }
    int off = ((m << 10) + (c << 4)) ^ ((m & 7) << 4);
    *(short8*)(hbuf + off) = hv;
  }
  __syncthreads();

  const int lane = tid & 63, wid = tid >> 6;
  const int lr = lane & 15, g = lane >> 4;

  int lin[4], xm[4];
  #pragma unroll
  for (int mf = 0; mf < 4; ++mf) {
    int row = mf * 16 + lr;
    lin[mf] = (row << 10) + (g << 4);
    xm[mf] = (row & 7) << 4;
  }
  int tv[4][4];
  #pragma unroll
  for (int mf = 0; mf < 4; ++mf)
    #pragma unroll
    for (int rr = 0; rr < 4; ++rr)
      tv[mf][rr] = tgt_s[mf * 16 + g * 4 + rr];

  float rsum[4][4];
  #pragma unroll
  for (int mf = 0; mf < 4; ++mf)
    #pragma unroll
    for (int rr = 0; rr < 4; ++rr) rsum[mf][rr] = 0.f;

  #pragma unroll
  for (int sc = 0; sc < 2; ++sc) {
    const int n0 = wid * 128 + sc * 64;
    const short* bptr[4];
    float bpv[4];
    #pragma unroll
    for (int nf = 0; nf < 4; ++nf) {
      bptr[nf] = WpB + (n0 / 16 + nf) * 8192 + lane * 8;   // frag-linear
      bpv[nf] = bp[n0 + nf * 16 + lr] * LOG2E;             // scaled bias
    }
    f32x4 acc[4][4];
    #pragma unroll
    for (int mf = 0; mf < 4; ++mf)
      #pragma unroll
      for (int nf = 0; nf < 4; ++nf)
        acc[mf][nf] = (f32x4){0.f, 0.f, 0.f, 0.f};

    #pragma unroll 2
    for (int kk = 0; kk < 16; ++kk) {
      bf16x8 av[4], bv[4];
      #pragma unroll
      for (int mf = 0; mf < 4; ++mf) {
        int off = (lin[mf] + (kk << 6)) ^ xm[mf];
        av[mf] = __builtin_bit_cast(bf16x8, *(const short8*)(hbuf + off));
      }
      #pragma unroll
      for (int nf = 0; nf < 4; ++nf)
        bv[nf] = __builtin_bit_cast(bf16x8, *(const short8*)(bptr[nf] + kk * 512));
      __builtin_amdgcn_s_setprio(1);          // T5: favor MFMA burst
      #pragma unroll
      for (int mf = 0; mf < 4; ++mf)
        #pragma unroll
        for (int nf = 0; nf < 4; ++nf)
          acc[mf][nf] = __builtin_amdgcn_mfma_f32_16x16x32_bf16(av[mf], bv[nf], acc[mf][nf], 0, 0, 0);
      __builtin_amdgcn_s_setprio(0);
    }
    // fold: base-2 sum-of-exp2 over this 64-col subchunk (scaled logits)
    #pragma unroll
    for (int mf = 0; mf < 4; ++mf)
      #pragma unroll
      for (int rr = 0; rr < 4; ++rr) {
        float x0 = __builtin_fmaf(acc[mf][0][rr], LOG2E, bpv[0]);
        float x1 = __builtin_fmaf(acc[mf][1][rr], LOG2E, bpv[1]);
        float x2 = __builtin_fmaf(acc[mf][2][rr], LOG2E, bpv[2]);
        float x3 = __builtin_fmaf(acc[mf][3][rr], LOG2E, bpv[3]);
        int rowl = mf * 16 + g * 4 + rr;
        if (wid == 0 && sc == 0 && lr == 0) l0_s[rowl] = x0;  // v = 0 (scaled)
        int dtv = tv[mf][rr] - n0;
        if (dtv >= 0 && dtv < 64 && (dtv & 15) == lr) {
          int nfi = dtv >> 4;
          lt_s[rowl] = (nfi == 0) ? x0 : (nfi == 1) ? x1 : (nfi == 2) ? x2 : x3;
        }
        rsum[mf][rr] += __builtin_amdgcn_exp2f(x0) + __builtin_amdgcn_exp2f(x1)
                      + __builtin_amdgcn_exp2f(x2) + __builtin_amdgcn_exp2f(x3);
      }
  }
  // add-butterfly across the 16 lanes of each group
  #pragma unroll
  for (int mf = 0; mf < 4; ++mf)
    #pragma unroll
    for (int rr = 0; rr < 4; ++rr) {
      float s_ = rsum[mf][rr];
      #pragma unroll
      for (int o = 1; o < 16; o <<= 1) s_ += __shfl_xor(s_, o);
      if (lr == 0) ws_s[wid][mf * 16 + g * 4 + rr] = s_;
    }
  __syncthreads();
  if (tid < JROWS) {
    int bo = bld_off[tid];
    if (bo >= 0) {
      float S = 0.f;
      #pragma unroll
      for (int w = 0; w < 8; ++w) S += ws_s[w][tid];
      float lse2v = __builtin_amdgcn_logf(S);   // log2
      lpb_d[bo] = l0_s[tid] - lse2v;            // LOG2 DOMAIN
      int eo = eld_off[tid];
      if (eo >= 0) lpe_d[eo] = lt_s[tid] - lse2v;
    }
  }
}

// ---------------- Kernel 3: alpha wavefront DP + loss (2-step composed) -----
// 1 block x 256 threads; wave w owns batch b=w, fully independent. The serial
// chain is the limit (r7: ~230 cy/step inferred). 2-step composition:
// a_{d+2}[u] = lse3(a_d[u]+T1, a_d[u-1]+T2, a_d[u-2]+T3) with T1/T2/T3
// alpha-independent (computed off-chain). Halves the chain length. All math
// in LOG2 domain (lp arrives as lp/ln2); final loss x ln2 once.
#define ACHUNK 16   /* diag rows per LDS chunk = 8 rounds */
#define NCHUNK 24   /* 24*16 = 384 rows -> 192 rounds = 384 steps >= 380 */
#define LB_FLOATS (ACHUNK * UP1)    /* 1296 */
#define LE_FLOATS (ACHUNK * U_DIM)  /* 1280 */
#define LE_BASE   (2 * B_DIM * LB_FLOATS) /* 10368 */
__global__ __launch_bounds__(256) void alpha_kernel(
    const float* __restrict__ lpb_d, const float* __restrict__ lpe_d,
    const int* __restrict__ ilen, const int* __restrict__ ulen_,
    float* __restrict__ out) {
  extern __shared__ float sbuf[];  // 82432 B: Lb[2][4][1296] + Le[2][4][1280]
  __shared__ float lls[B_DIM];
  const int tid = threadIdx.x;
  const int b = tid >> 6;
  const int lane = tid & 63;
  const float NEG = -1e30f;
  const int tl = ilen[b], ul = ulen_[b];
  const int dstar = tl - 1 + ul;          // final-cell diagonal

  const int u0 = lane;           // slot 0: u = 0..63
  const int u1 = 64 + lane;      // slot 1: u = 64..80 (lane < 17)
  const bool act1 = (u1 <= 80);

  const float* pb = lpb_d + (size_t)b * (NDIAG_B * UP1);
  const float4* pb4 = (const float4*)pb;
  const float4* pe4 = (const float4*)(lpe_d + (size_t)b * (NDIAG_E * U_DIM));
  const int PB4MAX = (NDIAG_B * UP1) / 4 - 1;   // 7694
  const int PE4MAX = (NDIAG_E * U_DIM) / 4 - 1; // 7579

  float4 rb[6], re[5];

  #define LOAD_CHUNK(c)                                                     \
    {                                                                       \
      int gb_ = (c) * (LB_FLOATS / 4), ge_ = (c) * (LE_FLOATS / 4);         \
      _Pragma("unroll")                                                     \
      for (int i = 0; i < 6; ++i) {                                         \
        int v = i * 64 + lane;                                              \
        if (v < LB_FLOATS / 4) {                                            \
          int gv = gb_ + v; if (gv > PB4MAX) gv = PB4MAX;                   \
          rb[i] = pb4[gv];                                                  \
        }                                                                   \
      }                                                                     \
      _Pragma("unroll")                                                     \
      for (int i = 0; i < 5; ++i) {                                         \
        int v = i * 64 + lane;                                              \
        int gv = ge_ + v; if (gv > PE4MAX) gv = PE4MAX;                     \
        re[i] = pe4[gv];                                                    \
      }                                                                     \
    }
  #define WRITE_CHUNK(c)                                                    \
    {                                                                       \
      int h_ = (c) & 1;                                                     \
      float* Lb_ = sbuf + (h_ * B_DIM + b) * LB_FLOATS;                     \
      float* Le_ = sbuf + LE_BASE + (h_ * B_DIM + b) * LE_FLOATS;           \
      _Pragma("unroll")                                                     \
      for (int i = 0; i < 6; ++i) {                                         \
        int v = i * 64 + lane;                                              \
        if (v < LB_FLOATS / 4) *(float4*)(Lb_ + v * 4) = rb[i];             \
      }                                                                     \
      _Pragma("unroll")                                                     \
      for (int i = 0; i < 5; ++i) {                                         \
        int v = i * 64 + lane;                                              \
        *(float4*)(Le_ + v * 4) = re[i];                                    \
      }                                                                     \
    }

  LOAD_CHUNK(0);
  WRITE_CHUNK(0);

  float pa0 = (u0 == 0) ? 0.f : NEG;  // alpha on diag 0 (log2 domain)
  float pa1 = NEG;
  float fin = NEG;
  if (dstar == 0 && u0 == ul) fin = pa0;   // tl=1, ul=0 corner

  // slot-1 clamped column indices (constant per lane)
  const int uc1 = act1 ? u1 : 80;

  for (int c = 0; c < NCHUNK; ++c) {
    if (c + 1 < NCHUNK) LOAD_CHUNK(c + 1);   // issue early, no wait
    const int h = c & 1;
    const float* Lb = sbuf + (h * B_DIM + b) * LB_FLOATS;
    const float* Le = sbuf + LE_BASE + (h * B_DIM + b) * LE_FLOATS;
    #pragma unroll
    for (int q = 0; q < 8; ++q) {
      const int j = 2 * q;
      const int s1 = c * ACHUNK + j + 1;   // steps s1, s1+1 this round
      // shuffles of a_{s1-1} (all parallel, off none of each other)
      float s0m1 = __shfl(pa0, (lane + 63) & 63);
      float s0m2 = __shfl(pa0, (lane + 62) & 63);
      float s1m1 = __shfl(pa1, (lane + 63) & 63);
      float s1m2 = __shfl(pa1, (lane + 62) & 63);
      float na0, na1;
      float b1_0, e1_0, b1_1, e1_1;        // saved for odd-diag capture
      // ---- slot 0 (u = lane) ----
      {
        const int u = u0;
        const int um1 = (u >= 1) ? u - 1 : 0;
        const int um2 = (u >= 2) ? u - 2 : 0;
        const int t1 = s1 - u;             // t2 = t1 + 1
        float b1 = Lb[j * UP1 + u],  b1m = Lb[j * UP1 + um1], b2 = Lb[(j + 1) * UP1 + u];
        float e1 = Le[j * U_DIM + um1], e1m = Le[j * U_DIM + um2], e2 = Le[(j + 1) * U_DIM + um1];
        b1  = (t1 >= 1 && t1 <= T_DIM - 1) ? b1 : NEG;
        b2  = (t1 >= 0 && t1 <= T_DIM - 2) ? b2 : NEG;            // 1<=t1+1<=299
        e1  = (t1 >= 0 && t1 <= T_DIM - 1 && u >= 1) ? e1 : NEG;
        e2  = (t1 >= -1 && t1 <= T_DIM - 2 && u >= 1) ? e2 : NEG; // 0<=t1+1<=299
        b1m = (t1 >= 0 && t1 <= T_DIM - 2 && u >= 1) ? b1m : NEG; // t@(s1,u-1)=t1+1
        e1m = (t1 >= -1 && t1 <= T_DIM - 2 && u >= 2) ? e1m : NEG;
        b1_0 = b1; e1_0 = e1;
        float T1 = b1 + b2;
        float T2 = lse2_2(e1 + b2, b1m + e2);
        float T3 = e1m + e2;
        float p0 = pa0 + T1;
        float p1 = (u >= 1) ? s0m1 + T2 : NEG;
        float p2 = (u >= 2) ? s0m2 + T3 : NEG;
        float mx = fmaxf(fmaxf(p0, p1), p2);
        float ss = __builtin_amdgcn_exp2f(p0 - mx) + __builtin_amdgcn_exp2f(p1 - mx)
                 + __builtin_amdgcn_exp2f(p2 - mx);
        na0 = mx + __builtin_amdgcn_logf(ss);
      }
      // ---- slot 1 (u = 64 + lane, clamped when inactive) ----
      {
        const int u = uc1;
        const int t1 = s1 - u1;            // use TRUE u for masks
        float b1 = Lb[j * UP1 + u],  b1m = Lb[j * UP1 + (u - 1)], b2 = Lb[(j + 1) * UP1 + u];
        float e1 = Le[j * U_DIM + (u - 1)], e1m = Le[j * U_DIM + (u - 2)], e2 = Le[(j + 1) * U_DIM + (u - 1)];
        b1  = (act1 && t1 >= 1 && t1 <= T_DIM - 1) ? b1 : NEG;
        b2  = (act1 && t1 >= 0 && t1 <= T_DIM - 2) ? b2 : NEG;
        e1  = (act1 && t1 >= 0 && t1 <= T_DIM - 1) ? e1 : NEG;
        e2  = (act1 && t1 >= -1 && t1 <= T_DIM - 2) ? e2 : NEG;
        b1m = (act1 && t1 >= 0 && t1 <= T_DIM - 2) ? b1m : NEG;
        e1m = (act1 && t1 >= -1 && t1 <= T_DIM - 2) ? e1m : NEG;
        b1_1 = b1; e1_1 = e1;
        float pm1 = (lane == 0) ? s0m1 : s1m1;   // a[u1-1]
        float pm2 = (lane <= 1) ? s0m2 : s1m2;   // a[u1-2]
        float T1 = b1 + b2;
        float T2 = lse2_2(e1 + b2, b1m + e2);
        float T3 = e1m + e2;
        float p0 = pa1 + T1;
        float p1 = pm1 + T2;
        float p2 = pm2 + T3;
        float mx = fmaxf(fmaxf(p0, p1), p2);
        float ss = __builtin_amdgcn_exp2f(p0 - mx) + __builtin_amdgcn_exp2f(p1 - mx)
                 + __builtin_amdgcn_exp2f(p2 - mx);
        na1 = act1 ? (mx + __builtin_amdgcn_logf(ss)) : NEG;
      }
      // odd-diagonal final capture: a_{s1}[ul] via one 2-term step
      if (s1 == dstar) {
        float pm1_0 = (u0 >= 1) ? s0m1 : NEG;
        float vo0 = lse2_2(pa0 + b1_0, pm1_0 + e1_0);
        if (u0 == ul) fin = vo0;
        float pm1_1 = (lane == 0) ? s0m1 : s1m1;
        float vo1 = lse2_2(pa1 + b1_1, pm1_1 + e1_1);
        if (act1 && u1 == ul) fin = vo1;
      }
      pa0 = na0; pa1 = na1;
      // even-diagonal final capture: a_{s1+1}
      if (s1 + 1 == dstar) {
        if (u0 == ul) fin = pa0;
        if (act1 && u1 == ul) fin = pa1;
      }
    }
    if (c + 1 < NCHUNK) WRITE_CHUNK(c + 1);  // vmcnt wait lands here, covered
  }

  #pragma unroll
  for (int o = 32; o; o >>= 1) fin = fmaxf(fin, __shfl_xor(fin, o));
  if (lane == 0) {
    float last = pb[(size_t)(tl - 1 + ul) * UP1 + ul];   // log2 domain
    lls[b] = fin + last;
  }
  __syncthreads();
  if (tid == 0)
    out[0] = -(lls[0] + lls[1] + lls[2] + lls[3]) * (LN2 * 0.25f);
}

// ---------------- launcher ----------------
extern "C" void kernel_launch(void* const* d_in, const int* in_sizes, int n_in,
                              void* d_out, int out_size, void* d_ws, size_t ws_size,
                              hipStream_t stream) {
  const float* enc = (const float*)d_in[0];
  const float* dec = (const float*)d_in[1];
  const float* Wf  = (const float*)d_in[2];
  const float* bfv = (const float*)d_in[3];
  const float* Wp  = (const float*)d_in[4];
  const float* bp  = (const float*)d_in[5];
  const int* targets = (const int*)d_in[6];
  const int* ilen    = (const int*)d_in[7];
  const int* ulen    = (const int*)d_in[8];
  float* out = (float*)d_out;
  char* ws = (char*)d_ws;

  short* WfB   = (short*)(ws + 0);          //   655360 B (packed)
  short* WpB   = (short*)(ws + 655360);     //  1048576 B (packed) -> 1703936
  short* epB   = (short*)(ws + 1703936);    //  1228800 B (bf16)   -> 2932736
  short* dpB   = (short*)(ws + 2932736);    //   331776 B (bf16)   -> 3264512
  float* lpb_d = (float*)(ws + 3264512);    //   492480 B (4*380*81) -> 3756992
  float* lpe_d = (float*)(ws + 3756992);    //   485120 B (4*379*80) -> 4242112

  cvt_kernel<<<832, 256, 0, stream>>>(Wf, Wp, WfB, WpB);
  proj_kernel<<<50, 256, 0, stream>>>(enc, dec, WfB, bfv, epB, dpB);
  joint_kernel<<<(NROWS + JROWS - 1) / JROWS, 512, 65536, stream>>>(epB, dpB, WpB, bp, targets, lpb_d, lpe_d);
  alpha_kernel<<<1, 256, 82432, stream>>>(lpb_d, lpe_d, ilen, ulen, out);
}

// Round 9
// 225.369 us; speedup vs baseline: 1.1279x; 1.1189x over previous
//
#include <hip/hip_runtime.h>

#define B_DIM 4
#define T_DIM 300
#define U_DIM 80
#define UP1   81
#define V_DIM 1024
#define NINNER 512
#define NROWS (B_DIM * T_DIM * UP1)   /* 97200 */
#define EP_ROWS (B_DIM * T_DIM)       /* 1200 */
#define DP_ROWS (B_DIM * UP1)         /* 324 */
#define NDIAG_B 380                    /* t+u diagonals for lpb */
#define NDIAG_E 379                    /* t+u diagonals for lpe */
#define WF_PART 163840                 /* 512 cols x 320 k, per half of Wf */
#define LOG2E 1.44269504088896341f
#define LN2   0.69314718055994531f

typedef float f32x4 __attribute__((ext_vector_type(4)));
typedef short short8 __attribute__((ext_vector_type(8)));
typedef short short4v __attribute__((ext_vector_type(4)));
typedef __bf16 bf16x8 __attribute__((ext_vector_type(8)));

static __device__ __forceinline__ short f2bf(float f) {
  return (short)__builtin_bit_cast(unsigned short, (__bf16)f);  // native cvt (RNE)
}
static __device__ __forceinline__ float bf2f(short s) {
  unsigned int u = ((unsigned int)(unsigned short)s) << 16;
  return __builtin_bit_cast(float, u);
}
static __device__ __forceinline__ float tanh_fast(float x) {
  float e = __builtin_amdgcn_exp2f(x * 2.88539008177792681f); // exp(2x)
  return 1.0f - 2.0f * __builtin_amdgcn_rcpf(e + 1.0f);
}
// base-2 logsumexp of 2 terms (NEG-safe)
static __device__ __forceinline__ float lse2_2(float a, float b) {
  float mx = fmaxf(a, b), mn = fminf(a, b);
  return mx + __builtin_amdgcn_logf(1.0f + __builtin_amdgcn_exp2f(mn - mx));
}

// ---------------- Kernel 0: weights fp32 -> bf16, MFMA-frag-linear pack -----
__global__ __launch_bounds__(256) void cvt_kernel(
    const float* __restrict__ Wf, const float* __restrict__ Wp,
    short* __restrict__ WfB, short* __restrict__ WpB) {
  int idx = blockIdx.x * 256 + threadIdx.x;
  const int nf = (512 * 640) / 4;   // 81920
  const int np = (V_DIM * NINNER) / 4;
  if (idx < nf) {
    float4 v = ((const float4*)Wf)[idx];
    int flat = idx * 4;
    int c = flat / 640;
    int kc = flat - c * 640;
    int part = (kc >= 320);
    int k0 = kc - (part ? 320 : 0);
    int dest = (part ? WF_PART : 0)
             + ((c >> 4) * 10 + (k0 >> 5)) * 512
             + (((k0 >> 3) & 3) * 16 + (c & 15)) * 8 + (k0 & 7);
    short4v o;
    o[0] = f2bf(v.x); o[1] = f2bf(v.y); o[2] = f2bf(v.z); o[3] = f2bf(v.w);
    *(short4v*)(WfB + dest) = o;
  } else if (idx < nf + np) {
    int j = idx - nf;
    float4 v = ((const float4*)Wp)[j];
    int flat = j * 4;
    int c = flat >> 9;
    int k0 = flat & 511;
    int dest = ((c >> 4) * 16 + (k0 >> 5)) * 512
             + (((k0 >> 3) & 3) * 16 + (c & 15)) * 8 + (k0 & 7);
    short4v o;
    o[0] = f2bf(v.x); o[1] = f2bf(v.y); o[2] = f2bf(v.z); o[3] = f2bf(v.w);
    *(short4v*)(WpB + dest) = o;
  }
}

// ---------------- Kernel 1: enc/dec projections (MFMA bf16) ----------------
// NOTE: no min-waves arg — min-waves>=4 on MFMA kernels splits the unified
// RF (Arch 64 / AGPR 64) and spills (r2/r3).
#define EP_BLOCKS 19
__global__ __launch_bounds__(256) void proj_kernel(
    const float* __restrict__ enc, const float* __restrict__ dec,
    const short* __restrict__ WfB, const float* __restrict__ bfv,
    short* __restrict__ epB, short* __restrict__ dpB) {
  const int half = blockIdx.x & 1;
  const int ob = blockIdx.x >> 1;
  const bool is_dp = (ob >= EP_BLOCKS);
  const int row0 = (is_dp ? ob - EP_BLOCKS : ob) * 64;
  const int nrows = is_dp ? DP_ROWS : EP_ROWS;
  const float* __restrict__ src = is_dp ? dec : enc;
  const short* __restrict__ bb = WfB + (is_dp ? WF_PART : 0);  // packed
  short* __restrict__ out = is_dp ? dpB : epB;

  __shared__ short As[64 * 320];  // 40 KB, XOR-swizzled
  const int tid = threadIdx.x;

  #pragma unroll
  for (int it = 0; it < 10; ++it) {
    int chunk = it * 256 + tid;        // 2560 chunks of 8 elems
    int m = chunk / 40;
    int c = chunk - m * 40;
    int r = row0 + m;
    short8 hv;
    #pragma unroll
    for (int j = 0; j < 8; ++j) hv[j] = 0;
    if (r < nrows) {
      const float* p = src + (size_t)r * 320 + c * 8;
      float4 a0 = *(const float4*)p;
      float4 a1 = *(const float4*)(p + 4);
      hv[0] = f2bf(a0.x); hv[1] = f2bf(a0.y); hv[2] = f2bf(a0.z); hv[3] = f2bf(a0.w);
      hv[4] = f2bf(a1.x); hv[5] = f2bf(a1.y); hv[6] = f2bf(a1.z); hv[7] = f2bf(a1.w);
    }
    int off = (m * 640 + c * 16) ^ ((m & 7) << 4);
    *(short8*)((char*)As + off) = hv;
  }
  __syncthreads();

  const int lane = tid & 63, wid = tid >> 6;
  const int lr = lane & 15, g = lane >> 4;

  int lin[4], xm[4];
  #pragma unroll
  for (int mf = 0; mf < 4; ++mf) {
    int row = mf * 16 + lr;
    lin[mf] = row * 640 + g * 16;
    xm[mf] = (row & 7) << 4;
  }

  const int n0 = half * 256 + wid * 64;
  const short* bptr[4];
  float bfc[4];
  #pragma unroll
  for (int nf2 = 0; nf2 < 4; ++nf2) {
    bptr[nf2] = bb + (n0 / 16 + nf2) * 5120 + lane * 8;   // frag-linear
    bfc[nf2] = is_dp ? bfv[n0 + nf2 * 16 + lr] : 0.f;
  }
  f32x4 acc[4][4];
  #pragma unroll
  for (int mf = 0; mf < 4; ++mf)
    #pragma unroll
    for (int nf2 = 0; nf2 < 4; ++nf2)
      acc[mf][nf2] = (f32x4){0.f, 0.f, 0.f, 0.f};

  #pragma unroll 2
  for (int kk = 0; kk < 10; ++kk) {
    bf16x8 av[4], bv[4];
    #pragma unroll
    for (int mf = 0; mf < 4; ++mf) {
      int off = (lin[mf] + (kk << 6)) ^ xm[mf];
      av[mf] = __builtin_bit_cast(bf16x8, *(const short8*)((const char*)As + off));
    }
    #pragma unroll
    for (int nf2 = 0; nf2 < 4; ++nf2)
      bv[nf2] = __builtin_bit_cast(bf16x8, *(const short8*)(bptr[nf2] + kk * 512));
    #pragma unroll
    for (int mf = 0; mf < 4; ++mf)
      #pragma unroll
      for (int nf2 = 0; nf2 < 4; ++nf2)
        acc[mf][nf2] = __builtin_amdgcn_mfma_f32_16x16x32_bf16(av[mf], bv[nf2], acc[mf][nf2], 0, 0, 0);
  }
  #pragma unroll
  for (int mf = 0; mf < 4; ++mf)
    #pragma unroll
    for (int nf2 = 0; nf2 < 4; ++nf2)
      #pragma unroll
      for (int rr = 0; rr < 4; ++rr) {
        int rowl = mf * 16 + g * 4 + rr;
        int grow = row0 + rowl;
        if (grow < nrows) {
          int col = n0 + nf2 * 16 + lr;
          out[(size_t)grow * NINNER + col] = f2bf(acc[mf][nf2][rr] + bfc[nf2]);
        }
      }
}

// ---------------- Kernel 2: fused joint + log-softmax slices ----------------
// (r8 validated: base-2 softmax, LOG2-domain outputs, T5 setprio)
#define JROWS 64
__global__ __launch_bounds__(512) void joint_kernel(
    const short* __restrict__ epB, const short* __restrict__ dpB,
    const short* __restrict__ WpB, const float* __restrict__ bp,
    const int* __restrict__ tgt,
    float* __restrict__ lpb_d, float* __restrict__ lpe_d) {
  extern __shared__ char hbuf[];  // 64 * 512 * 2 = 65536 B
  __shared__ int ep_off[JROWS], dp_off[JROWS], bld_off[JROWS], eld_off[JROWS], tgt_s[JROWS];
  __shared__ float l0_s[JROWS], lt_s[JROWS];
  __shared__ float ws_s[8][JROWS];

  const int tid = threadIdx.x;
  const int row0 = blockIdx.x * JROWS;

  if (tid < JROWS) {
    int gr = row0 + tid;
    if (gr < NROWS) {
      int b = gr / (T_DIM * UP1);
      int rem = gr - b * (T_DIM * UP1);
      int t = rem / UP1;
      int u = rem - t * UP1;
      ep_off[tid] = (b * T_DIM + t) * NINNER;
      dp_off[tid] = (b * UP1 + u) * NINNER;
      bld_off[tid] = (b * NDIAG_B + (t + u)) * UP1 + u;          // diag layout
      eld_off[tid] = (u < U_DIM) ? ((b * NDIAG_E + (t + u)) * U_DIM + u) : -1;
      tgt_s[tid] = (u < U_DIM) ? tgt[b * U_DIM + u] : 0;
    } else {
      ep_off[tid] = 0; dp_off[tid] = 0; bld_off[tid] = -1; eld_off[tid] = -1; tgt_s[tid] = 0;
    }
    l0_s[tid] = 0.f; lt_s[tid] = 0.f;
  }
  __syncthreads();

  // Phase A: h = tanh(ep+dp) into LDS (bf16 in, bf16 out, swizzled)
  #pragma unroll 2
  for (int it = 0; it < 8; ++it) {
    int chunk = it * 512 + tid;    // 4096 chunks of 8
    int m = chunk >> 6, c = chunk & 63;
    short8 hv;
    #pragma unroll
    for (int j = 0; j < 8; ++j) hv[j] = 0;
    if (bld_off[m] >= 0) {
      short8 ev = *(const short8*)(epB + ep_off[m] + c * 8);
      short8 dv = *(const short8*)(dpB + dp_off[m] + c * 8);
      #pragma unroll
      for (int j = 0; j < 8; ++j)
        hv[j] = f2bf(tanh_fast(bf2f(ev[j]) + bf2f(dv[j])));
    }
    int off = ((m << 10) + (c << 4)) ^ ((m & 7) << 4);
    *(short8*)(hbuf + off) = hv;
  }
  __syncthreads();

  const int lane = tid & 63, wid = tid >> 6;
  const int lr = lane & 15, g = lane >> 4;

  int lin[4], xm[4];
  #pragma unroll
  for (int mf = 0; mf < 4; ++mf) {
    int row = mf * 16 + lr;
    lin[mf] = (row << 10) + (g << 4);
    xm[mf] = (row & 7) << 4;
  }
  int tv[4][4];
  #pragma unroll
  for (int mf = 0; mf < 4; ++mf)
    #pragma unroll
    for (int rr = 0; rr < 4; ++rr)
      tv[mf][rr] = tgt_s[mf * 16 + g * 4 + rr];

  float rsum[4][4];
  #pragma unroll
  for (int mf = 0; mf < 4; ++mf)
    #pragma unroll
    for (int rr = 0; rr < 4; ++rr) rsum[mf][rr] = 0.f;

  #pragma unroll
  for (int sc = 0; sc < 2; ++sc) {
    const int n0 = wid * 128 + sc * 64;
    const short* bptr[4];
    float bpv[4];
    #pragma unroll
    for (int nf = 0; nf < 4; ++nf) {
      bptr[nf] = WpB + (n0 / 16 + nf) * 8192 + lane * 8;   // frag-linear
      bpv[nf] = bp[n0 + nf * 16 + lr] * LOG2E;             // scaled bias
    }
    f32x4 acc[4][4];
    #pragma unroll
    for (int mf = 0; mf < 4; ++mf)
      #pragma unroll
      for (int nf = 0; nf < 4; ++nf)
        acc[mf][nf] = (f32x4){0.f, 0.f, 0.f, 0.f};

    #pragma unroll 2
    for (int kk = 0; kk < 16; ++kk) {
      bf16x8 av[4], bv[4];
      #pragma unroll
      for (int mf = 0; mf < 4; ++mf) {
        int off = (lin[mf] + (kk << 6)) ^ xm[mf];
        av[mf] = __builtin_bit_cast(bf16x8, *(const short8*)(hbuf + off));
      }
      #pragma unroll
      for (int nf = 0; nf < 4; ++nf)
        bv[nf] = __builtin_bit_cast(bf16x8, *(const short8*)(bptr[nf] + kk * 512));
      __builtin_amdgcn_s_setprio(1);          // T5: favor MFMA burst
      #pragma unroll
      for (int mf = 0; mf < 4; ++mf)
        #pragma unroll
        for (int nf = 0; nf < 4; ++nf)
          acc[mf][nf] = __builtin_amdgcn_mfma_f32_16x16x32_bf16(av[mf], bv[nf], acc[mf][nf], 0, 0, 0);
      __builtin_amdgcn_s_setprio(0);
    }
    // fold: base-2 sum-of-exp2 over this 64-col subchunk (scaled logits)
    #pragma unroll
    for (int mf = 0; mf < 4; ++mf)
      #pragma unroll
      for (int rr = 0; rr < 4; ++rr) {
        float x0 = __builtin_fmaf(acc[mf][0][rr], LOG2E, bpv[0]);
        float x1 = __builtin_fmaf(acc[mf][1][rr], LOG2E, bpv[1]);
        float x2 = __builtin_fmaf(acc[mf][2][rr], LOG2E, bpv[2]);
        float x3 = __builtin_fmaf(acc[mf][3][rr], LOG2E, bpv[3]);
        int rowl = mf * 16 + g * 4 + rr;
        if (wid == 0 && sc == 0 && lr == 0) l0_s[rowl] = x0;  // v = 0 (scaled)
        int dtv = tv[mf][rr] - n0;
        if (dtv >= 0 && dtv < 64 && (dtv & 15) == lr) {
          int nfi = dtv >> 4;
          lt_s[rowl] = (nfi == 0) ? x0 : (nfi == 1) ? x1 : (nfi == 2) ? x2 : x3;
        }
        rsum[mf][rr] += __builtin_amdgcn_exp2f(x0) + __builtin_amdgcn_exp2f(x1)
                      + __builtin_amdgcn_exp2f(x2) + __builtin_amdgcn_exp2f(x3);
      }
  }
  // add-butterfly across the 16 lanes of each group
  #pragma unroll
  for (int mf = 0; mf < 4; ++mf)
    #pragma unroll
    for (int rr = 0; rr < 4; ++rr) {
      float s_ = rsum[mf][rr];
      #pragma unroll
      for (int o = 1; o < 16; o <<= 1) s_ += __shfl_xor(s_, o);
      if (lr == 0) ws_s[wid][mf * 16 + g * 4 + rr] = s_;
    }
  __syncthreads();
  if (tid < JROWS) {
    int bo = bld_off[tid];
    if (bo >= 0) {
      float S = 0.f;
      #pragma unroll
      for (int w = 0; w < 8; ++w) S += ws_s[w][tid];
      float lse2v = __builtin_amdgcn_logf(S);   // log2
      lpb_d[bo] = l0_s[tid] - lse2v;            // LOG2 DOMAIN
      int eo = eld_off[tid];
      if (eo >= 0) lpe_d[eo] = lt_s[tid] - lse2v;
    }
  }
}

// ---------------- Kernel 3: alpha DP, register-resident operands (r9) -------
// r8 lesson: chain-halving was null -> per-round ds-pipe overhead dominates
// (12 LDS reads + 4 bpermutes/round at ~120cy single-outstanding, 1 wave/SIMD).
// r9: NO LDS. 8 operand streams/slot loaded straight into NAMED registers
// (static indices only — rule #20), double-buffered A/B, chunk = 8 diag rows
// = 4 composed rounds. Only ds-pipe ops left: 4 alpha shuffles/round.
// Masks/math identical to r8 (validated absmax 0). LOG2 domain.
#define ACH 8
#define NCH 48   /* 48*8 = 384 rows; steps to d=384 >= dstar max 379 */
__global__ __launch_bounds__(256) void alpha_kernel(
    const float* __restrict__ lpb_d, const float* __restrict__ lpe_d,
    const int* __restrict__ ilen, const int* __restrict__ ulen_,
    float* __restrict__ out) {
  __shared__ float lls[B_DIM];
  const int tid = threadIdx.x;
  const int b = tid >> 6;
  const int lane = tid & 63;
  const float NEG = -1e30f;
  const int tl = ilen[b], ul = ulen_[b];
  const int dstar = tl - 1 + ul;          // final-cell diagonal

  const int u0 = lane;           // slot 0: u = 0..63
  const int u1 = 64 + lane;      // slot 1: u = 64..80 (lane < 17)
  const bool act1 = (u1 <= 80);
  const int uc1 = act1 ? u1 : 80;

  const float* pb = lpb_d + (size_t)b * (NDIAG_B * UP1);
  const float* pe = lpe_d + (size_t)b * (NDIAG_E * U_DIM);

  // register buffers: per slot {blank@u, blank@u-1, emit@u-1, emit@u-2}
  float Ab0r[ACH], Ab0m[ACH], Ae0r[ACH], Ae0m[ACH];
  float Ab1r[ACH], Ab1m[ACH], Ae1r[ACH], Ae1m[ACH];
  float Bb0r[ACH], Bb0m[ACH], Be0r[ACH], Be0m[ACH];
  float Bb1r[ACH], Bb1m[ACH], Be1r[ACH], Be1m[ACH];

  // negative column indices at lanes 0/1 read adjacent ws regions (safe,
  // mapped) and are masked to NEG at use.
  #define ALOAD(P, c)                                                        \
    {                                                                        \
      _Pragma("unroll")                                                      \
      for (int j = 0; j < ACH; ++j) {                                        \
        int dd = (c) * ACH + j;                                              \
        int ddb = dd < NDIAG_B ? dd : NDIAG_B - 1;                           \
        int dde = dd < NDIAG_E ? dd : NDIAG_E - 1;                           \
        const float* rb_ = pb + ddb * UP1;                                   \
        const float* re_ = pe + dde * U_DIM;                                 \
        P##b0r[j] = rb_[u0];                                                 \
        P##b0m[j] = rb_[u0 - 1];                                             \
        P##e0r[j] = re_[u0 - 1];                                             \
        P##e0m[j] = re_[u0 - 2];                                             \
        P##b1r[j] = rb_[uc1];                                                \
        P##b1m[j] = rb_[uc1 - 1];                                            \
        P##e1r[j] = re_[uc1 - 1];                                            \
        P##e1m[j] = re_[uc1 - 2];                                            \
      }                                                                      \
    }

  #define ACOMP(P, c)                                                        \
    {                                                                        \
      _Pragma("unroll")                                                      \
      for (int q = 0; q < ACH / 2; ++q) {                                    \
        const int j = 2 * q;                                                 \
        const int s1 = (c) * ACH + j + 1;                                    \
        float s0m1 = __shfl(pa0, (lane + 63) & 63);                          \
        float s0m2 = __shfl(pa0, (lane + 62) & 63);                          \
        float s1m1 = __shfl(pa1, (lane + 63) & 63);                          \
        float s1m2 = __shfl(pa1, (lane + 62) & 63);                          \
        float na0, na1;                                                      \
        float b1_0, e1_0, b1_1, e1_1;                                        \
        { /* slot 0 */                                                       \
          const int u = u0;                                                  \
          const int t1 = s1 - u;                                             \
          float b1 = (t1 >= 1 && t1 <= T_DIM - 1) ? P##b0r[j] : NEG;         \
          float b2 = (t1 >= 0 && t1 <= T_DIM - 2) ? P##b0r[j + 1] : NEG;     \
          float e1 = (t1 >= 0 && t1 <= T_DIM - 1 && u >= 1) ? P##e0r[j] : NEG; \
          float e2 = (t1 >= -1 && t1 <= T_DIM - 2 && u >= 1) ? P##e0r[j + 1] : NEG; \
          float b1m = (t1 >= 0 && t1 <= T_DIM - 2 && u >= 1) ? P##b0m[j] : NEG; \
          float e1m = (t1 >= -1 && t1 <= T_DIM - 2 && u >= 2) ? P##e0m[j] : NEG; \
          b1_0 = b1; e1_0 = e1;                                              \
          float T1 = b1 + b2;                                                \
          float T2 = lse2_2(e1 + b2, b1m + e2);                              \
          float T3 = e1m + e2;                                               \
          float p0 = pa0 + T1;                                               \
          float p1 = (u >= 1) ? s0m1 + T2 : NEG;                             \
          float p2 = (u >= 2) ? s0m2 + T3 : NEG;                             \
          float mx = fmaxf(fmaxf(p0, p1), p2);                               \
          float ss = __builtin_amdgcn_exp2f(p0 - mx)                         \
                   + __builtin_amdgcn_exp2f(p1 - mx)                         \
                   + __builtin_amdgcn_exp2f(p2 - mx);                        \
          na0 = mx + __builtin_amdgcn_logf(ss);                              \
        }                                                                    \
        { /* slot 1 */                                                       \
          const int t1 = s1 - u1;                                            \
          float b1 = (act1 && t1 >= 1 && t1 <= T_DIM - 1) ? P##b1r[j] : NEG; \
          float b2 = (act1 && t1 >= 0 && t1 <= T_DIM - 2) ? P##b1r[j + 1] : NEG; \
          float e1 = (act1 && t1 >= 0 && t1 <= T_DIM - 1) ? P##e1r[j] : NEG; \
          float e2 = (act1 && t1 >= -1 && t1 <= T_DIM - 2) ? P##e1r[j + 1] : NEG; \
          float b1m = (act1 && t1 >= 0 && t1 <= T_DIM - 2) ? P##b1m[j] : NEG; \
          float e1m = (act1 && t1 >= -1 && t1 <= T_DIM - 2) ? P##e1m[j] : NEG; \
          b1_1 = b1; e1_1 = e1;                                              \
          float pm1 = (lane == 0) ? s0m1 : s1m1;                             \
          float pm2 = (lane <= 1) ? s0m2 : s1m2;                             \
          float T1 = b1 + b2;                                                \
          float T2 = lse2_2(e1 + b2, b1m + e2);                              \
          float T3 = e1m + e2;                                               \
          float p0 = pa1 + T1;                                               \
          float p1 = pm1 + T2;                                               \
          float p2 = pm2 + T3;                                               \
          float mx = fmaxf(fmaxf(p0, p1), p2);                               \
          float ss = __builtin_amdgcn_exp2f(p0 - mx)                         \
                   + __builtin_amdgcn_exp2f(p1 - mx)                         \
                   + __builtin_amdgcn_exp2f(p2 - mx);                        \
          na1 = act1 ? (mx + __builtin_amdgcn_logf(ss)) : NEG;               \
        }                                                                    \
        if (s1 == dstar) { /* odd-diagonal final capture */                  \
          float pm1_0 = (u0 >= 1) ? s0m1 : NEG;                              \
          float vo0 = lse2_2(pa0 + b1_0, pm1_0 + e1_0);                      \
          if (u0 == ul) fin = vo0;                                           \
          float pm1_1 = (lane == 0) ? s0m1 : s1m1;                           \
          float vo1 = lse2_2(pa1 + b1_1, pm1_1 + e1_1);                      \
          if (act1 && u1 == ul) fin = vo1;                                   \
        }                                                                    \
        pa0 = na0; pa1 = na1;                                                \
        if (s1 + 1 == dstar) { /* even-diagonal final capture */             \
          if (u0 == ul) fin = pa0;                                           \
          if (act1 && u1 == ul) fin = pa1;                                   \
        }                                                                    \
      }                                                                      \
    }

  float pa0 = (u0 == 0) ? 0.f : NEG;  // alpha on diag 0 (log2 domain)
  float pa1 = NEG;
  float fin = NEG;
  if (dstar == 0 && u0 == ul) fin = pa0;   // tl=1, ul=0 corner

  ALOAD(A, 0);
  for (int p = 0; p < NCH / 2; ++p) {
    const int cA = 2 * p, cB = 2 * p + 1;
    ALOAD(B, cB);        // issue next chunk's loads (covered by ACOMP(A))
    ACOMP(A, cA);
    ALOAD(A, cA + 2);    // chunk 48 clamps to row 379/378 — harmless
    ACOMP(B, cB);
  }

  #pragma unroll
  for (int o = 32; o; o >>= 1) fin = fmaxf(fin, __shfl_xor(fin, o));
  if (lane == 0) {
    float last = pb[(size_t)dstar * UP1 + ul];   // log2 domain
    lls[b] = fin + last;
  }
  __syncthreads();
  if (tid == 0)
    out[0] = -(lls[0] + lls[1] + lls[2] + lls[3]) * (LN2 * 0.25f);
}

// ---------------- launcher ----------------
extern "C" void kernel_launch(void* const* d_in, const int* in_sizes, int n_in,
                              void* d_out, int out_size, void* d_ws, size_t ws_size,
                              hipStream_t stream) {
  const float* enc = (const float*)d_in[0];
  const float* dec = (const float*)d_in[1];
  const float* Wf  = (const float*)d_in[2];
  const float* bfv = (const float*)d_in[3];
  const float* Wp  = (const float*)d_in[4];
  const float* bp  = (const float*)d_in[5];
  const int* targets = (const int*)d_in[6];
  const int* ilen    = (const int*)d_in[7];
  const int* ulen    = (const int*)d_in[8];
  float* out = (float*)d_out;
  char* ws = (char*)d_ws;

  short* WfB   = (short*)(ws + 0);          //   655360 B (packed)
  short* WpB   = (short*)(ws + 655360);     //  1048576 B (packed) -> 1703936
  short* epB   = (short*)(ws + 1703936);    //  1228800 B (bf16)   -> 2932736
  short* dpB   = (short*)(ws + 2932736);    //   331776 B (bf16)   -> 3264512
  float* lpb_d = (float*)(ws + 3264512);    //   492480 B (4*380*81) -> 3756992
  float* lpe_d = (float*)(ws + 3756992);    //   485120 B (4*379*80) -> 4242112

  cvt_kernel<<<832, 256, 0, stream>>>(Wf, Wp, WfB, WpB);
  proj_kernel<<<50, 256, 0, stream>>>(enc, dec, WfB, bfv, epB, dpB);
  joint_kernel<<<(NROWS + JROWS - 1) / JROWS, 512, 65536, stream>>>(epB, dpB, WpB, bp, targets, lpb_d, lpe_d);
  alpha_kernel<<<1, 256, 0, stream>>>(lpb_d, lpe_d, ilen, ulen, out);
}